// Round 4
// baseline (58.348 us; speedup 1.0000x reference)
//
#include <hip/hip_runtime.h>
#include <math.h>

// B=2048, N=16384, D=16
#define BB 2048
#define NN 16384
#define KAUG 32                 // augmented K (18 used, padded to MFMA K=32)
#define RSA 40                  // A LDS row stride in ushorts (80 B) -> conflict-free b128
#define RSX 32                  // X LDS row stride in ushorts (64 B)
#define NSLICES 128             // 128 slices x 128 n
#define CHUNKS 8                // 8 x 16-n chunks per slice
#define BT 2                    // b-tiles per wave (32 samples)
#define LN2 0.6931471805599453f
#define LOG2E 1.4426950408889634f
#define LN2PI 1.8378770664093453f

typedef __attribute__((ext_vector_type(8))) short bf16x8;
typedef __attribute__((ext_vector_type(4))) float f32x4;

__device__ __forceinline__ float EXP2(float v) { return __builtin_amdgcn_exp2f(v); }

__device__ __forceinline__ ushort f2bf(float f) {
    unsigned u = __float_as_uint(f);
    return (ushort)((u + 0x7FFFu + ((u >> 16) & 1u)) >> 16);   // RNE
}
__device__ __forceinline__ float bf2f(ushort h) {
    return __uint_as_float(((unsigned)h) << 16);
}

// ---------------------------------------------------------------------------
// Single fused kernel. Grid = 128 slices x 16 bgrps = 2048 blocks x 256 thr.
// Phase 1: block preps its slice's 128 A-rows + its bgrp's 128 X-rows
//          (augmented, split hi/lo bf16) into LDS — one row per thread.
// Phase 2: 4 waves x (2 b-tiles x 128 n): split-bf16 MFMA gives the base-2
//          exponent directly; online LSE per lane; butterfly over lane-groups.
// Phase 3: partials -> global; last block per bgrp (device-scope atomic,
//          works for ANY counter init via mod-128) reduces 128 slices -> out.
// ---------------------------------------------------------------------------
__global__ __launch_bounds__(256, 4) void kde_fused(
    const float* __restrict__ x, const float* __restrict__ mu,
    const float* __restrict__ sigt, const float* __restrict__ wt,
    float2* __restrict__ part, unsigned int* __restrict__ cnt,
    float* __restrict__ out)
{
    __shared__ ushort AhL[128 * RSA], AlL[128 * RSA];   // 10 KB + 10 KB
    __shared__ ushort XhL[128 * RSX], XlL[128 * RSX];   //  8 KB +  8 KB
    __shared__ int lastFlag;

    const int tid   = threadIdx.x;
    const int slice = blockIdx.x >> 4;
    const int bgrp  = blockIdx.x & 15;

    // ---------------- phase 1: prep one augmented row per thread ----------
    {
        float v[KAUG];
        #pragma unroll
        for (int k = 18; k < KAUG; ++k) v[k] = 0.f;
        ushort *dh, *dl;
        if (tid < 128) {
            int n = slice * 128 + tid;
            const float4* m4 = (const float4*)(mu + (size_t)n * 16);
            float4 a = m4[0], b = m4[1], c = m4[2], d = m4[3];
            float r[16];
            *(float4*)(r + 0) = a; *(float4*)(r + 4) = b;
            *(float4*)(r + 8) = c; *(float4*)(r + 12) = d;
            float musq = 0.f;
            #pragma unroll
            for (int k = 0; k < 16; ++k) musq = fmaf(r[k], r[k], musq);
            float stv = sigt[n], wv = wt[n];
            float sigma = expf(stv);
            float A2 = -0.5f * LOG2E / (sigma * sigma);
            float C2 = -LOG2E * (16.f * stv + 8.f * LN2PI) + log2f(wv);
            #pragma unroll
            for (int k = 0; k < 16; ++k) v[k] = A2 * (-2.f * r[k]);
            v[16] = fmaf(A2, musq, C2);
            v[17] = A2;
            dh = AhL + tid * RSA;
            dl = AlL + tid * RSA;
        } else {
            int b = bgrp * 128 + (tid - 128);
            const float4* x4 = (const float4*)(x + (size_t)b * 16);
            float4 a = x4[0], bb = x4[1], c = x4[2], d = x4[3];
            float r[16];
            *(float4*)(r + 0) = a;  *(float4*)(r + 4) = bb;
            *(float4*)(r + 8) = c;  *(float4*)(r + 12) = d;
            float xsq = 0.f;
            #pragma unroll
            for (int k = 0; k < 16; ++k) { v[k] = r[k]; xsq = fmaf(r[k], r[k], xsq); }
            v[16] = 1.0f;
            v[17] = xsq;
            dh = XhL + (tid - 128) * RSX;
            dl = XlL + (tid - 128) * RSX;
        }
        unsigned uh[16], ul[16];
        #pragma unroll
        for (int k = 0; k < 16; ++k) {
            ushort h0 = f2bf(v[2*k]),   h1 = f2bf(v[2*k+1]);
            ushort l0 = f2bf(v[2*k]   - bf2f(h0));
            ushort l1 = f2bf(v[2*k+1] - bf2f(h1));
            uh[k] = (unsigned)h0 | ((unsigned)h1 << 16);
            ul[k] = (unsigned)l0 | ((unsigned)l1 << 16);
        }
        uint4* ph = (uint4*)dh;
        uint4* pl = (uint4*)dl;
        #pragma unroll
        for (int k = 0; k < 4; ++k) {
            ph[k] = make_uint4(uh[4*k], uh[4*k+1], uh[4*k+2], uh[4*k+3]);
            pl[k] = make_uint4(ul[4*k], ul[4*k+1], ul[4*k+2], ul[4*k+3]);
        }
    }
    __syncthreads();

    // ---------------- phase 2: MFMA + online LSE --------------------------
    const int lane = tid & 63;
    const int wv   = tid >> 6;
    const int l15  = lane & 15, g = lane >> 4;

    bf16x8 bh[BT], bl[BT];
    #pragma unroll
    for (int bt = 0; bt < BT; ++bt) {
        int xr = wv * 32 + bt * 16 + l15;
        bh[bt] = *(const bf16x8*)(XhL + xr * RSX + g * 8);
        bl[bt] = *(const bf16x8*)(XlL + xr * RSX + g * 8);
    }

    float m[BT], s[BT];
    #pragma unroll
    for (int bt = 0; bt < BT; ++bt) { m[bt] = -INFINITY; s[bt] = 0.f; }

    #pragma unroll 2
    for (int c = 0; c < CHUNKS; ++c) {
        int ar = c * 16 + l15;
        bf16x8 ah = *(const bf16x8*)(AhL + ar * RSA + g * 8);
        bf16x8 al = *(const bf16x8*)(AlL + ar * RSA + g * 8);
        #pragma unroll
        for (int bt = 0; bt < BT; ++bt) {
            f32x4 acc = {0.f, 0.f, 0.f, 0.f};
            acc = __builtin_amdgcn_mfma_f32_16x16x32_bf16(al, bh[bt], acc, 0, 0, 0);
            acc = __builtin_amdgcn_mfma_f32_16x16x32_bf16(ah, bl[bt], acc, 0, 0, 0);
            acc = __builtin_amdgcn_mfma_f32_16x16x32_bf16(ah, bh[bt], acc, 0, 0, 0);
            float cmax = fmaxf(fmaxf(acc[0], acc[1]), fmaxf(acc[2], acc[3]));
            float mn = fmaxf(m[bt], cmax);
            float e0 = EXP2(acc[0] - mn), e1 = EXP2(acc[1] - mn);
            float e2 = EXP2(acc[2] - mn), e3 = EXP2(acc[3] - mn);
            float rr = EXP2(m[bt] - mn);
            float t  = (e0 + e1) + (e2 + e3);
            s[bt] = fmaf(s[bt], rr, t);
            m[bt] = mn;
        }
    }

    // merge the 4 lane-groups, write partial (m,s) per b
    #pragma unroll
    for (int bt = 0; bt < BT; ++bt) {
        float mm = m[bt], ss = s[bt];
        #pragma unroll
        for (int off = 16; off <= 32; off <<= 1) {
            float mo = __shfl_xor(mm, off, 64);
            float so = __shfl_xor(ss, off, 64);
            float mn = fmaxf(mm, mo);
            ss = ss * EXP2(mm - mn) + so * EXP2(mo - mn);
            mm = mn;
        }
        if (lane < 16) {
            int b = bgrp * 128 + wv * 32 + bt * 16 + lane;
            part[(size_t)slice * BB + b] = make_float2(mm, ss);
        }
    }

    // ---------------- phase 3: last-block final reduction ------------------
    __syncthreads();
    if (tid == 0) {
        __threadfence();                                   // release partials
        unsigned old = atomicAdd(&cnt[bgrp], 1u);
        lastFlag = ((old & 127u) == 127u) ? 1 : 0;         // exact for ANY init
    }
    __syncthreads();
    if (lastFlag && tid < 128) {
        __threadfence();                                   // acquire partials
        int b = bgrp * 128 + tid;
        float mm = -INFINITY, ss = 0.f;
        #pragma unroll 4
        for (int k = 0; k < NSLICES; ++k) {
            float2 vv = part[(size_t)k * BB + b];
            float mn = fmaxf(mm, vv.x);
            ss = fmaf(ss, EXP2(mm - mn), vv.y * EXP2(vv.x - mn));
            mm = mn;
        }
        out[b] = (mm + log2f(ss)) * LN2;
    }
}

extern "C" void kernel_launch(void* const* d_in, const int* in_sizes, int n_in,
                              void* d_out, int out_size, void* d_ws, size_t ws_size,
                              hipStream_t stream) {
    const float* x  = (const float*)d_in[0];
    const float* mu = (const float*)d_in[1];
    const float* st = (const float*)d_in[2];
    const float* w  = (const float*)d_in[3];
    float* out = (float*)d_out;

    char* ws = (char*)d_ws;
    float2* part = (float2*)ws;                            // 128*2048*8 = 2 MB
    unsigned int* cnt = (unsigned int*)(ws + (2u << 20));  // 16 counters (any init ok)

    hipLaunchKernelGGL(kde_fused, dim3(NSLICES * 16), dim3(256), 0, stream,
                       x, mu, st, w, part, cnt, out);
}

// Round 5
// 25.259 us; speedup vs baseline: 2.3100x; 2.3100x over previous
//
#include <hip/hip_runtime.h>
#include <math.h>

// B=2048, N=16384, D=16
#define BB 2048
#define NN 16384
#define KAUG 32                 // augmented K (18 used, padded to MFMA K=32)
#define RSA 40                  // A LDS row stride in ushorts (80 B)
#define RSX 32                  // X LDS row stride in ushorts (64 B)
#define NSLICES 128             // 128 slices x 128 n
#define CHUNKS 8                // 8 x 16-n chunks per slice
#define BT 2                    // b-tiles per wave (32 samples)
#define LN2 0.6931471805599453f
#define LOG2E 1.4426950408889634f
#define LN2PI 1.8378770664093453f

typedef __attribute__((ext_vector_type(8))) short bf16x8;
typedef __attribute__((ext_vector_type(4))) float f32x4;

__device__ __forceinline__ float EXP2(float v) { return __builtin_amdgcn_exp2f(v); }

__device__ __forceinline__ ushort f2bf(float f) {
    unsigned u = __float_as_uint(f);
    return (ushort)((u + 0x7FFFu + ((u >> 16) & 1u)) >> 16);   // RNE
}
__device__ __forceinline__ float bf2f(ushort h) {
    return __uint_as_float(((unsigned)h) << 16);
}

// ---------------------------------------------------------------------------
// K1: fused prep + MFMA + online LSE -> partials. NO cross-block comm.
// Grid = 128 slices x 16 bgrps = 2048 blocks x 256 thr.
// Phase 1: block preps its slice's 128 A-rows + its bgrp's 128 X-rows
//          (augmented, split hi/lo bf16) into LDS — one row per thread.
// Phase 2: 4 waves x (2 b-tiles x 128 n): split-bf16 MFMA gives the base-2
//          exponent directly; online LSE per lane; butterfly merge; write
//          (m,s) partial per (slice, b).
// ---------------------------------------------------------------------------
__global__ __launch_bounds__(256, 4) void kde_main(
    const float* __restrict__ x, const float* __restrict__ mu,
    const float* __restrict__ sigt, const float* __restrict__ wt,
    float2* __restrict__ part)
{
    __shared__ ushort AhL[128 * RSA], AlL[128 * RSA];   // 10 KB + 10 KB
    __shared__ ushort XhL[128 * RSX], XlL[128 * RSX];   //  8 KB +  8 KB

    const int tid   = threadIdx.x;
    const int slice = blockIdx.x >> 4;
    const int bgrp  = blockIdx.x & 15;

    // ---------------- phase 1: prep one augmented row per thread ----------
    {
        float v[KAUG];
        #pragma unroll
        for (int k = 18; k < KAUG; ++k) v[k] = 0.f;
        ushort *dh, *dl;
        if (tid < 128) {
            int n = slice * 128 + tid;
            const float4* m4 = (const float4*)(mu + (size_t)n * 16);
            float4 a = m4[0], b = m4[1], c = m4[2], d = m4[3];
            float r[16];
            *(float4*)(r + 0) = a; *(float4*)(r + 4) = b;
            *(float4*)(r + 8) = c; *(float4*)(r + 12) = d;
            float musq = 0.f;
            #pragma unroll
            for (int k = 0; k < 16; ++k) musq = fmaf(r[k], r[k], musq);
            float stv = sigt[n], wv = wt[n];
            float sigma = expf(stv);
            float A2 = -0.5f * LOG2E / (sigma * sigma);
            float C2 = -LOG2E * (16.f * stv + 8.f * LN2PI) + log2f(wv);
            #pragma unroll
            for (int k = 0; k < 16; ++k) v[k] = A2 * (-2.f * r[k]);
            v[16] = fmaf(A2, musq, C2);
            v[17] = A2;
            dh = AhL + tid * RSA;
            dl = AlL + tid * RSA;
        } else {
            int b = bgrp * 128 + (tid - 128);
            const float4* x4 = (const float4*)(x + (size_t)b * 16);
            float4 a = x4[0], bb = x4[1], c = x4[2], d = x4[3];
            float r[16];
            *(float4*)(r + 0) = a;  *(float4*)(r + 4) = bb;
            *(float4*)(r + 8) = c;  *(float4*)(r + 12) = d;
            float xsq = 0.f;
            #pragma unroll
            for (int k = 0; k < 16; ++k) { v[k] = r[k]; xsq = fmaf(r[k], r[k], xsq); }
            v[16] = 1.0f;
            v[17] = xsq;
            dh = XhL + (tid - 128) * RSX;
            dl = XlL + (tid - 128) * RSX;
        }
        unsigned uh[16], ul[16];
        #pragma unroll
        for (int k = 0; k < 16; ++k) {
            ushort h0 = f2bf(v[2*k]),   h1 = f2bf(v[2*k+1]);
            ushort l0 = f2bf(v[2*k]   - bf2f(h0));
            ushort l1 = f2bf(v[2*k+1] - bf2f(h1));
            uh[k] = (unsigned)h0 | ((unsigned)h1 << 16);
            ul[k] = (unsigned)l0 | ((unsigned)l1 << 16);
        }
        uint4* ph = (uint4*)dh;
        uint4* pl = (uint4*)dl;
        #pragma unroll
        for (int k = 0; k < 4; ++k) {
            ph[k] = make_uint4(uh[4*k], uh[4*k+1], uh[4*k+2], uh[4*k+3]);
            pl[k] = make_uint4(ul[4*k], ul[4*k+1], ul[4*k+2], ul[4*k+3]);
        }
    }
    __syncthreads();

    // ---------------- phase 2: MFMA + online LSE --------------------------
    const int lane = tid & 63;
    const int wv   = tid >> 6;
    const int l15  = lane & 15, g = lane >> 4;

    bf16x8 bh[BT], bl[BT];
    #pragma unroll
    for (int bt = 0; bt < BT; ++bt) {
        int xr = wv * 32 + bt * 16 + l15;
        bh[bt] = *(const bf16x8*)(XhL + xr * RSX + g * 8);
        bl[bt] = *(const bf16x8*)(XlL + xr * RSX + g * 8);
    }

    float m[BT], s[BT];
    #pragma unroll
    for (int bt = 0; bt < BT; ++bt) { m[bt] = -INFINITY; s[bt] = 0.f; }

    #pragma unroll 2
    for (int c = 0; c < CHUNKS; ++c) {
        int ar = c * 16 + l15;
        bf16x8 ah = *(const bf16x8*)(AhL + ar * RSA + g * 8);
        bf16x8 al = *(const bf16x8*)(AlL + ar * RSA + g * 8);
        #pragma unroll
        for (int bt = 0; bt < BT; ++bt) {
            f32x4 acc = {0.f, 0.f, 0.f, 0.f};
            acc = __builtin_amdgcn_mfma_f32_16x16x32_bf16(al, bh[bt], acc, 0, 0, 0);
            acc = __builtin_amdgcn_mfma_f32_16x16x32_bf16(ah, bl[bt], acc, 0, 0, 0);
            acc = __builtin_amdgcn_mfma_f32_16x16x32_bf16(ah, bh[bt], acc, 0, 0, 0);
            float cmax = fmaxf(fmaxf(acc[0], acc[1]), fmaxf(acc[2], acc[3]));
            float mn = fmaxf(m[bt], cmax);
            float e0 = EXP2(acc[0] - mn), e1 = EXP2(acc[1] - mn);
            float e2 = EXP2(acc[2] - mn), e3 = EXP2(acc[3] - mn);
            float rr = EXP2(m[bt] - mn);
            float t  = (e0 + e1) + (e2 + e3);
            s[bt] = fmaf(s[bt], rr, t);
            m[bt] = mn;
        }
    }

    // merge the 4 lane-groups, write partial (m,s) per b
    #pragma unroll
    for (int bt = 0; bt < BT; ++bt) {
        float mm = m[bt], ss = s[bt];
        #pragma unroll
        for (int off = 16; off <= 32; off <<= 1) {
            float mo = __shfl_xor(mm, off, 64);
            float so = __shfl_xor(ss, off, 64);
            float mn = fmaxf(mm, mo);
            ss = ss * EXP2(mm - mn) + so * EXP2(mo - mn);
            mm = mn;
        }
        if (lane < 16) {
            int b = bgrp * 128 + wv * 32 + bt * 16 + lane;
            part[(size_t)slice * BB + b] = make_float2(mm, ss);
        }
    }
}

// ---------------------------------------------------------------------------
// K2: reduce. One thread per sample b; 128 slice-partials merged serially
// (coalesced loads: consecutive threads -> consecutive b). Deterministic.
// ---------------------------------------------------------------------------
__global__ __launch_bounds__(256) void kde_reduce(
    const float2* __restrict__ part, float* __restrict__ out)
{
    int b = blockIdx.x * 256 + threadIdx.x;
    float mm = -INFINITY, ss = 0.f;
    #pragma unroll 8
    for (int k = 0; k < NSLICES; ++k) {
        float2 vv = part[(size_t)k * BB + b];
        float mn = fmaxf(mm, vv.x);
        ss = fmaf(ss, EXP2(mm - mn), vv.y * EXP2(vv.x - mn));
        mm = mn;
    }
    out[b] = (mm + log2f(ss)) * LN2;
}

extern "C" void kernel_launch(void* const* d_in, const int* in_sizes, int n_in,
                              void* d_out, int out_size, void* d_ws, size_t ws_size,
                              hipStream_t stream) {
    const float* x  = (const float*)d_in[0];
    const float* mu = (const float*)d_in[1];
    const float* st = (const float*)d_in[2];
    const float* w  = (const float*)d_in[3];
    float* out = (float*)d_out;

    float2* part = (float2*)d_ws;                          // 128*2048*8 = 2 MB

    hipLaunchKernelGGL(kde_main, dim3(NSLICES * 16), dim3(256), 0, stream,
                       x, mu, st, w, part);
    hipLaunchKernelGGL(kde_reduce, dim3(BB / 256), dim3(256), 0, stream,
                       part, out);
}

// Round 6
// 24.393 us; speedup vs baseline: 2.3920x; 1.0355x over previous
//
#include <hip/hip_runtime.h>
#include <hip/hip_bf16.h>
#include <math.h>

// B=2048, N=16384, D=16
#define BB 2048
#define NN 16384
#define KAUG 32                 // augmented K (18 used, padded to MFMA K=32)
#define RSA 40                  // A LDS row stride in ushorts (80 B)
#define RSX 32                  // X LDS row stride in ushorts (64 B)
#define NSLICES 128             // 128 slices x 128 n
#define CHUNKS 8                // 8 x 16-n chunks per slice
#define BT 2                    // b-tiles per wave (32 samples)
#define LN2 0.6931471805599453f
#define LOG2E 1.4426950408889634f
#define LN2PI 1.8378770664093453f

typedef __attribute__((ext_vector_type(8))) short bf16x8;
typedef __attribute__((ext_vector_type(4))) float f32x4;

__device__ __forceinline__ float EXP2(float v) { return __builtin_amdgcn_exp2f(v); }

// pack two f32 -> one u32 of 2x bf16 (RNE) via v_cvt_pk_bf16_f32
__device__ __forceinline__ unsigned pack_bf2(float a, float b) {
    __hip_bfloat162 h = __float22bfloat162_rn(make_float2(a, b));
    union { __hip_bfloat162 h2; unsigned u; } cvt;
    cvt.h2 = h;
    return cvt.u;
}
__device__ __forceinline__ float lo16f(unsigned u) { return __uint_as_float(u << 16); }
__device__ __forceinline__ float hi16f(unsigned u) { return __uint_as_float(u & 0xFFFF0000u); }

// ---------------------------------------------------------------------------
// K1: fused prep + two-pass MFMA LSE -> partials. No cross-block comm.
// Grid = 128 slices x 16 bgrps = 2048 blocks x 256 thr.
// Phase 1: 128 threads prep A-rows (slice), 128 prep X-rows (bgrp) into LDS,
//          augmented split hi/lo bf16 so acc = base-2 exponent directly.
// Phase 2: pass 1 computes per-b max M (pure fmax, no chains);
//          pass 2 recomputes MFMAs and sums exp2(acc - M) (chain = adds only).
// ---------------------------------------------------------------------------
__global__ __launch_bounds__(256, 4) void kde_main(
    const float* __restrict__ x, const float* __restrict__ mu,
    const float* __restrict__ sigt, const float* __restrict__ wt,
    float2* __restrict__ part)
{
    __shared__ ushort AhL[128 * RSA], AlL[128 * RSA];   // 10 KB + 10 KB
    __shared__ ushort XhL[128 * RSX], XlL[128 * RSX];   //  8 KB +  8 KB

    const int tid   = threadIdx.x;
    const int slice = blockIdx.x >> 4;
    const int bgrp  = blockIdx.x & 15;

    // ---------------- phase 1: prep one augmented row per thread ----------
    {
        float v[KAUG];
        #pragma unroll
        for (int k = 18; k < KAUG; ++k) v[k] = 0.f;
        ushort *dh, *dl;
        if (tid < 128) {
            int n = slice * 128 + tid;
            const float4* m4 = (const float4*)(mu + (size_t)n * 16);
            float4 a = m4[0], b = m4[1], c = m4[2], d = m4[3];
            float r[16];
            *(float4*)(r + 0) = a; *(float4*)(r + 4) = b;
            *(float4*)(r + 8) = c; *(float4*)(r + 12) = d;
            float musq = 0.f;
            #pragma unroll
            for (int k = 0; k < 16; ++k) musq = fmaf(r[k], r[k], musq);
            float stv = sigt[n], wv = wt[n];
            // A2 = -0.5*log2e*exp(-2*st) ; exp(-2 st) = 2^(-2*st*log2e)
            float A2 = -0.5f * LOG2E * EXP2(-2.0f * LOG2E * stv);
            float C2 = -LOG2E * (16.f * stv + 8.f * LN2PI) + __log2f(wv);
            #pragma unroll
            for (int k = 0; k < 16; ++k) v[k] = A2 * (-2.f * r[k]);
            v[16] = fmaf(A2, musq, C2);
            v[17] = A2;
            dh = AhL + tid * RSA;
            dl = AlL + tid * RSA;
        } else {
            int b = bgrp * 128 + (tid - 128);
            const float4* x4 = (const float4*)(x + (size_t)b * 16);
            float4 a = x4[0], bb = x4[1], c = x4[2], d = x4[3];
            float r[16];
            *(float4*)(r + 0) = a;  *(float4*)(r + 4) = bb;
            *(float4*)(r + 8) = c;  *(float4*)(r + 12) = d;
            float xsq = 0.f;
            #pragma unroll
            for (int k = 0; k < 16; ++k) { v[k] = r[k]; xsq = fmaf(r[k], r[k], xsq); }
            v[16] = 1.0f;
            v[17] = xsq;
            dh = XhL + (tid - 128) * RSX;
            dl = XlL + (tid - 128) * RSX;
        }
        unsigned uh[16], ul[16];
        #pragma unroll
        for (int k = 0; k < 16; ++k) {
            unsigned h = pack_bf2(v[2*k], v[2*k+1]);
            unsigned l = pack_bf2(v[2*k]   - lo16f(h),
                                  v[2*k+1] - hi16f(h));
            uh[k] = h;  ul[k] = l;
        }
        uint4* ph = (uint4*)dh;
        uint4* pl = (uint4*)dl;
        #pragma unroll
        for (int k = 0; k < 4; ++k) {
            ph[k] = make_uint4(uh[4*k], uh[4*k+1], uh[4*k+2], uh[4*k+3]);
            pl[k] = make_uint4(ul[4*k], ul[4*k+1], ul[4*k+2], ul[4*k+3]);
        }
    }
    __syncthreads();

    // ---------------- phase 2: two-pass MFMA LSE ---------------------------
    const int lane = tid & 63;
    const int wv   = tid >> 6;
    const int l15  = lane & 15, g = lane >> 4;

    bf16x8 bh[BT], bl[BT];
    #pragma unroll
    for (int bt = 0; bt < BT; ++bt) {
        int xr = wv * 32 + bt * 16 + l15;
        bh[bt] = *(const bf16x8*)(XhL + xr * RSX + g * 8);
        bl[bt] = *(const bf16x8*)(XlL + xr * RSX + g * 8);
    }

    // pass 1: per-lane max (no exp2, no serial s-chain)
    float M0 = -INFINITY, M1 = -INFINITY;
    #pragma unroll 2
    for (int c = 0; c < CHUNKS; ++c) {
        int ar = c * 16 + l15;
        bf16x8 ah = *(const bf16x8*)(AhL + ar * RSA + g * 8);
        bf16x8 al = *(const bf16x8*)(AlL + ar * RSA + g * 8);
        {
            f32x4 acc = {0.f, 0.f, 0.f, 0.f};
            acc = __builtin_amdgcn_mfma_f32_16x16x32_bf16(al, bh[0], acc, 0, 0, 0);
            acc = __builtin_amdgcn_mfma_f32_16x16x32_bf16(ah, bl[0], acc, 0, 0, 0);
            acc = __builtin_amdgcn_mfma_f32_16x16x32_bf16(ah, bh[0], acc, 0, 0, 0);
            M0 = fmaxf(M0, fmaxf(fmaxf(acc[0], acc[1]), fmaxf(acc[2], acc[3])));
        }
        {
            f32x4 acc = {0.f, 0.f, 0.f, 0.f};
            acc = __builtin_amdgcn_mfma_f32_16x16x32_bf16(al, bh[1], acc, 0, 0, 0);
            acc = __builtin_amdgcn_mfma_f32_16x16x32_bf16(ah, bl[1], acc, 0, 0, 0);
            acc = __builtin_amdgcn_mfma_f32_16x16x32_bf16(ah, bh[1], acc, 0, 0, 0);
            M1 = fmaxf(M1, fmaxf(fmaxf(acc[0], acc[1]), fmaxf(acc[2], acc[3])));
        }
    }
    // merge max across the 4 lane-groups -> all g share M for each (l15, bt)
    M0 = fmaxf(M0, __shfl_xor(M0, 16, 64));
    M0 = fmaxf(M0, __shfl_xor(M0, 32, 64));
    M1 = fmaxf(M1, __shfl_xor(M1, 16, 64));
    M1 = fmaxf(M1, __shfl_xor(M1, 32, 64));

    // compiler barrier: force LDS re-read / forbid cross-pass MFMA CSE
    asm volatile("" ::: "memory");

    // pass 2: sum exp2(acc - M); only chain is an add per chunk
    float S0 = 0.f, S1 = 0.f;
    #pragma unroll 2
    for (int c = 0; c < CHUNKS; ++c) {
        int ar = c * 16 + l15;
        bf16x8 ah = *(const bf16x8*)(AhL + ar * RSA + g * 8);
        bf16x8 al = *(const bf16x8*)(AlL + ar * RSA + g * 8);
        {
            f32x4 acc = {0.f, 0.f, 0.f, 0.f};
            acc = __builtin_amdgcn_mfma_f32_16x16x32_bf16(al, bh[0], acc, 0, 0, 0);
            acc = __builtin_amdgcn_mfma_f32_16x16x32_bf16(ah, bl[0], acc, 0, 0, 0);
            acc = __builtin_amdgcn_mfma_f32_16x16x32_bf16(ah, bh[0], acc, 0, 0, 0);
            S0 += (EXP2(acc[0] - M0) + EXP2(acc[1] - M0))
                + (EXP2(acc[2] - M0) + EXP2(acc[3] - M0));
        }
        {
            f32x4 acc = {0.f, 0.f, 0.f, 0.f};
            acc = __builtin_amdgcn_mfma_f32_16x16x32_bf16(al, bh[1], acc, 0, 0, 0);
            acc = __builtin_amdgcn_mfma_f32_16x16x32_bf16(ah, bl[1], acc, 0, 0, 0);
            acc = __builtin_amdgcn_mfma_f32_16x16x32_bf16(ah, bh[1], acc, 0, 0, 0);
            S1 += (EXP2(acc[0] - M1) + EXP2(acc[1] - M1))
                + (EXP2(acc[2] - M1) + EXP2(acc[3] - M1));
        }
    }
    // sum-merge across lane-groups: plain adds (common M)
    S0 += __shfl_xor(S0, 16, 64);
    S0 += __shfl_xor(S0, 32, 64);
    S1 += __shfl_xor(S1, 16, 64);
    S1 += __shfl_xor(S1, 32, 64);

    if (lane < 16) {
        int b0 = bgrp * 128 + wv * 32 + lane;
        part[(size_t)slice * BB + b0]      = make_float2(M0, S0);
        part[(size_t)slice * BB + b0 + 16] = make_float2(M1, S1);
    }
}

// ---------------------------------------------------------------------------
// K2: reduce. One thread per sample b; 128 slice-partials merged via 4
// interleaved independent chains (latency / 4), then combined. Deterministic.
// ---------------------------------------------------------------------------
__global__ __launch_bounds__(256) void kde_reduce(
    const float2* __restrict__ part, float* __restrict__ out)
{
    int b = blockIdx.x * 256 + threadIdx.x;
    float mm[4], ss[4];
    #pragma unroll
    for (int j = 0; j < 4; ++j) { mm[j] = -INFINITY; ss[j] = 0.f; }
    #pragma unroll 4
    for (int k = 0; k < 32; ++k) {
        #pragma unroll
        for (int j = 0; j < 4; ++j) {
            float2 vv = part[(size_t)(k * 4 + j) * BB + b];
            float mn = fmaxf(mm[j], vv.x);
            ss[j] = fmaf(ss[j], EXP2(mm[j] - mn), vv.y * EXP2(vv.x - mn));
            mm[j] = mn;
        }
    }
    float mA = fmaxf(fmaxf(mm[0], mm[1]), fmaxf(mm[2], mm[3]));
    float sA = ss[0] * EXP2(mm[0] - mA) + ss[1] * EXP2(mm[1] - mA)
             + ss[2] * EXP2(mm[2] - mA) + ss[3] * EXP2(mm[3] - mA);
    out[b] = (mA + __log2f(sA)) * LN2;
}

extern "C" void kernel_launch(void* const* d_in, const int* in_sizes, int n_in,
                              void* d_out, int out_size, void* d_ws, size_t ws_size,
                              hipStream_t stream) {
    const float* x  = (const float*)d_in[0];
    const float* mu = (const float*)d_in[1];
    const float* st = (const float*)d_in[2];
    const float* w  = (const float*)d_in[3];
    float* out = (float*)d_out;

    float2* part = (float2*)d_ws;                          // 128*2048*8 = 2 MB

    hipLaunchKernelGGL(kde_main, dim3(NSLICES * 16), dim3(256), 0, stream,
                       x, mu, st, w, part);
    hipLaunchKernelGGL(kde_reduce, dim3(BB / 256), dim3(256), 0, stream,
                       part, out);
}